// Round 5
// baseline (25368.697 us; speedup 1.0000x reference)
//
#include <hip/hip_runtime.h>
#include <hip/hip_bf16.h>
#include <hip/hip_fp16.h>

// Problem constants
#define T_STEPS 8192
#define O_DIM   1024
#define H_DIM   2048
#define G3      6144      // 3*H
#define A_DIM   512
#define NWG     256       // workgroups in scan (1 per CU)
#define SLICE   8         // hidden indices per WG (= waves per WG)
#define NROWS   24        // 3 * SLICE rows of W_hh per WG
#define RPW     3         // rows per wave (r, z, n gate rows of own idx)

// X buffer rows: row t+1 holds xi[t] as fp16[6144]; hs[t] (fp32[2048]) is
// written into row t after its xi was consumed.
#define XROW_F32   3072

typedef _Float16 v2h __attribute__((ext_vector_type(2)));

__device__ __forceinline__ float dot8(uint4 w, uint4 h, float acc) {
#if defined(__has_builtin) && __has_builtin(__builtin_amdgcn_fdot2)
    acc = __builtin_amdgcn_fdot2(__builtin_bit_cast(v2h, w.x),
                                 __builtin_bit_cast(v2h, h.x), acc, false);
    acc = __builtin_amdgcn_fdot2(__builtin_bit_cast(v2h, w.y),
                                 __builtin_bit_cast(v2h, h.y), acc, false);
    acc = __builtin_amdgcn_fdot2(__builtin_bit_cast(v2h, w.z),
                                 __builtin_bit_cast(v2h, h.z), acc, false);
    acc = __builtin_amdgcn_fdot2(__builtin_bit_cast(v2h, w.w),
                                 __builtin_bit_cast(v2h, h.w), acc, false);
#else
    const __half2* wh = (const __half2*)&w;
    const __half2* hh = (const __half2*)&h;
    #pragma unroll
    for (int q = 0; q < 4; ++q) {
        float2 wf = __half22float2(wh[q]);
        float2 hf = __half22float2(hh[q]);
        acc = fmaf(wf.x, hf.x, acc);
        acc = fmaf(wf.y, hf.y, acc);
    }
#endif
    return acc;
}

// 64-lane sum, VALU-only (DPP). Validated numerically (v8/v9 passed).
__device__ __forceinline__ float dpp_sum64(float v) {
    float s = v;
    int x;
    x = __builtin_amdgcn_update_dpp(0, __builtin_bit_cast(int, s), 0x111, 0xF, 0xF, true);
    s += __builtin_bit_cast(float, x);
    x = __builtin_amdgcn_update_dpp(0, __builtin_bit_cast(int, s), 0x112, 0xF, 0xF, true);
    s += __builtin_bit_cast(float, x);
    x = __builtin_amdgcn_update_dpp(0, __builtin_bit_cast(int, s), 0x114, 0xF, 0xF, true);
    s += __builtin_bit_cast(float, x);
    x = __builtin_amdgcn_update_dpp(0, __builtin_bit_cast(int, s), 0x118, 0xF, 0xF, true);
    s += __builtin_bit_cast(float, x);
    x = __builtin_amdgcn_update_dpp(0, __builtin_bit_cast(int, s), 0x142, 0xF, 0xF, true); // row_bcast15
    s += __builtin_bit_cast(float, x);
    x = __builtin_amdgcn_update_dpp(0, __builtin_bit_cast(int, s), 0x143, 0xF, 0xF, true); // row_bcast31
    s += __builtin_bit_cast(float, x);
    return __builtin_bit_cast(float,
        __builtin_amdgcn_readlane(__builtin_bit_cast(int, s), 63));
}

// ---------------------------------------------------------------------------
// fp32 GEMM:  C[M,N] = A[M,K] @ B[N,K]^T + bias[N]
// 128x128 tile, BK=16, 256 threads, 8x8 per thread.
// OUT_HALF=1 stores C as fp16, else fp32. A row stride lda, C row stride ldc.
// ---------------------------------------------------------------------------
template <int OUT_HALF>
__global__ __launch_bounds__(256) void gemm_bt_bias(
    const float* __restrict__ A, int lda,
    const float* __restrict__ B,
    const float* __restrict__ bias,
    void* __restrict__ Cv, int ldc,
    int M, int N, int K)
{
    __shared__ float As[16][128];
    __shared__ float Bs[16][128];

    const int bm = blockIdx.y * 128;
    const int bn = blockIdx.x * 128;
    const int tid = threadIdx.x;
    const int tm = (tid >> 4) * 8;
    const int tn = (tid & 15) * 8;

    float acc[8][8] = {};

    for (int k0 = 0; k0 < K; k0 += 16) {
        #pragma unroll
        for (int u = 0; u < 2; ++u) {
            const int id = u * 256 + tid;
            const int r = id >> 2;
            const int c = (id & 3) << 2;
            float4 v = *(const float4*)(A + (size_t)(bm + r) * lda + k0 + c);
            As[c + 0][r] = v.x; As[c + 1][r] = v.y;
            As[c + 2][r] = v.z; As[c + 3][r] = v.w;
        }
        #pragma unroll
        for (int u = 0; u < 2; ++u) {
            const int id = u * 256 + tid;
            const int r = id >> 2;
            const int c = (id & 3) << 2;
            float4 v = *(const float4*)(B + (size_t)(bn + r) * K + k0 + c);
            Bs[c + 0][r] = v.x; Bs[c + 1][r] = v.y;
            Bs[c + 2][r] = v.z; Bs[c + 3][r] = v.w;
        }
        __syncthreads();

        #pragma unroll
        for (int kk = 0; kk < 16; ++kk) {
            float a[8], b[8];
            #pragma unroll
            for (int i = 0; i < 8; ++i) a[i] = As[kk][tm + i];
            #pragma unroll
            for (int j = 0; j < 8; ++j) b[j] = Bs[kk][tn + j];
            #pragma unroll
            for (int i = 0; i < 8; ++i)
                #pragma unroll
                for (int j = 0; j < 8; ++j)
                    acc[i][j] = fmaf(a[i], b[j], acc[i][j]);
        }
        __syncthreads();
    }

    if (OUT_HALF) {
        __half* C = (__half*)Cv;
        #pragma unroll
        for (int i = 0; i < 8; ++i) {
            const size_t row = (size_t)(bm + tm + i) * ldc;
            __half tmp[8];
            #pragma unroll
            for (int j = 0; j < 8; ++j)
                tmp[j] = __float2half(acc[i][j] + bias[bn + tn + j]);
            *(uint4*)(C + row + bn + tn) = *(const uint4*)tmp;
        }
    } else {
        float* C = (float*)Cv;
        #pragma unroll
        for (int i = 0; i < 8; ++i) {
            const size_t row = (size_t)(bm + tm + i) * ldc;
            #pragma unroll
            for (int j0 = 0; j0 < 8; j0 += 4) {
                const int n = bn + tn + j0;
                float4 v;
                v.x = acc[i][j0 + 0] + bias[n + 0];
                v.y = acc[i][j0 + 1] + bias[n + 1];
                v.z = acc[i][j0 + 2] + bias[n + 2];
                v.w = acc[i][j0 + 3] + bias[n + 3];
                *(float4*)(C + row + n) = v;
            }
        }
    }
}

// ---------------------------------------------------------------------------
// Persistent cooperative GRU scan, v10 = v9 + hierarchical epoch flag.
// 256 WGs x 512 threads (8 waves). Wave w of WG g owns hidden idx i=8g+w,
// i.e. W_hh rows {w, 8+w, 16+w} (fp16, LDS-resident, 96 KiB).
//
// v9 post-mortem: compute-side changes (DPP reduce) were neutral -> the
// ~4700-cycle step is dominated by store->visibility->discovery. All 256
// WGs polling the full 8KB packet array every ~800 cycles = ~5-7 TB/s of
// agent-scope L3 poll traffic, inflating latencies and amplifying
// straggler jitter (each WG's discovery noise feeds the next step).
//
// v10: WG0 is the checker. After WG0's packet poll + barrier certify all
// 2048 tags >= t, its wave0 stores t into 64 replicated flag lines
// (64B-strided). WGs 1..255 first spin on one 4B flag copy (1 cacheline
// per WG per iter -> ~85x poll-traffic cut), then run the UNCHANGED packet
// verification loop (passes in ~1 iteration). The flag is purely advisory:
// correctness still rests solely on the per-packet tag check, so all v5
// invariants hold unchanged. Deadlock-free by induction: all stores of
// tag t+1 exist => WG0's poll(t+1) passes => flag(t+1) => all flag-waits
// pass => all polls pass => all store t+2.
// ---------------------------------------------------------------------------
__global__ __launch_bounds__(512) void gru_scan(
    const __half*  __restrict__ xiX,     // X as fp16 rows (stride 6144)
    float*         __restrict__ hsX,     // X as fp32 rows (stride 3072)
    const float*   __restrict__ W_hh,    // [6144, 2048]
    const float*   __restrict__ b_hh,    // [6144]
    unsigned*      __restrict__ pairs,   // [2][2048] packets, pre-zeroed
    unsigned*      __restrict__ flags)   // 64 replicated epoch lines, zeroed
{
    const int g    = blockIdx.x;
    const int tid  = threadIdx.x;
    const int wave = tid >> 6;
    const int lane = tid & 63;
    const int my_i = g * SLICE + wave;   // hidden index owned by this wave

    __shared__ __align__(16) __half w_lds[NROWS][H_DIM];   // 96 KiB
    __shared__ __align__(16) __half h_lds[2][H_DIM];       // 8 KiB

    // ---- preload W_hh slice -> fp16 LDS (coalesced float4 loads) ----------
    for (int l = 0; l < NROWS; ++l) {
        const int grow = (l >> 3) * H_DIM + g * SLICE + (l & 7);
        float4 v = *(const float4*)(W_hh + (size_t)grow * H_DIM + tid * 4);
        __half tmp[4] = { __float2half(v.x), __float2half(v.y),
                          __float2half(v.z), __float2half(v.w) };
        *(uint2*)(&w_lds[l][tid * 4]) = *(const uint2*)tmp;
    }
    float bh_r = 0.f, bh_z = 0.f, bh_n = 0.f;
    if (lane == 0) {
        bh_r = b_hh[my_i];
        bh_z = b_hh[H_DIM + my_i];
        bh_n = b_hh[2 * H_DIM + my_i];
    }
    __syncthreads();

    float h_own = 0.f;   // lane0: fp32 hidden value of own index
    // Each non-checker WG spins on its own replicated flag line (16 u32 =
    // 64B stride) to avoid a single hot cacheline.
    unsigned* const my_flag = flags + (size_t)(g & 63) * 16;

    for (int t = 0; t < T_STEPS; ++t) {
        // lane0: prefetch xi for this step (row t+1 of X), plain cached loads
        float xr = 0.f, xz = 0.f, xn = 0.f;
        if (lane == 0) {
            const __half* xp = xiX + (size_t)(t + 1) * G3 + my_i;
            xr = __half2float(xp[0]);
            xz = __half2float(xp[H_DIM]);
            xn = __half2float(xp[2 * H_DIM]);
        }

        // issue weight ds_reads now: LDS port works during the wait
        uint4 wv[RPW][4];
        #pragma unroll
        for (int r = 0; r < RPW; ++r)
            #pragma unroll
            for (int j = 0; j < 4; ++j)
                wv[r][j] = *(const uint4*)(&w_lds[r * 8 + wave][j * 512 + lane * 8]);

        // non-checker WGs: cheap epoch gate (1 cacheline/iter) before the
        // full packet verification. Purely advisory — correctness comes
        // from the tag loop below.
        if (g != 0) {
            const unsigned tgt = (unsigned)t;
            for (;;) {
                unsigned f = __hip_atomic_load(my_flag, __ATOMIC_RELAXED,
                                               __HIP_MEMORY_SCOPE_AGENT);
                if (f >= tgt) break;
                __builtin_amdgcn_s_sleep(1);
            }
        }

        // poll own chunk of 256 packets (4/lane), stage bits into h_lds[t&1]
        {
            const unsigned long long* pp = (const unsigned long long*)
                (pairs + (size_t)(t & 1) * H_DIM + wave * 256 + lane * 4);
            const unsigned tgt = (unsigned)t;
            unsigned long long p0, p1;
            for (;;) {
                p0 = __hip_atomic_load(pp + 0, __ATOMIC_RELAXED,
                                       __HIP_MEMORY_SCOPE_AGENT);
                p1 = __hip_atomic_load(pp + 1, __ATOMIC_RELAXED,
                                       __HIP_MEMORY_SCOPE_AGENT);
                bool ok = (((unsigned)(p0 >> 16) & 0xFFFFu) >= tgt) &&
                          (((unsigned)(p0 >> 48))           >= tgt) &&
                          (((unsigned)(p1 >> 16) & 0xFFFFu) >= tgt) &&
                          (((unsigned)(p1 >> 48))           >= tgt);
                if (__all(ok)) break;
                __builtin_amdgcn_s_sleep(1);
            }
            const unsigned long long hbits =
                  (p0 & 0xFFFFull)
                | ((p0 >> 32) & 0xFFFFull) << 16
                | ((p1 & 0xFFFFull) << 32)
                | ((p1 >> 32) & 0xFFFFull) << 48;
            *(unsigned long long*)(&h_lds[t & 1][wave * 256 + lane * 4]) = hbits;
        }
        __syncthreads();   // h_lds[t&1] ready; WG0: all tags >= t certified

        // checker WG: broadcast epoch t to the 64 replicated flag lines.
        // Fire-and-forget stores; matvec below hides their latency.
        if (g == 0 && tid < 64)
            __hip_atomic_store(flags + (size_t)tid * 16, (unsigned)t,
                               __ATOMIC_RELAXED, __HIP_MEMORY_SCOPE_AGENT);

        // matvec: 3 rows x 2048 via fp16 dot2, fp32 accumulate
        uint4 hv[4];
        #pragma unroll
        for (int j = 0; j < 4; ++j)
            hv[j] = *(const uint4*)(&h_lds[t & 1][j * 512 + lane * 8]);

        float acc[RPW] = {0.f, 0.f, 0.f};
        #pragma unroll
        for (int r = 0; r < RPW; ++r)
            #pragma unroll
            for (int j = 0; j < 4; ++j)
                acc[r] = dot8(wv[r][j], hv[j], acc[r]);

        // 64-lane sum per row, DPP-only
        #pragma unroll
        for (int r = 0; r < RPW; ++r)
            acc[r] = dpp_sum64(acc[r]);

        // lane0: gates + publish
        if (lane == 0) {
            const float ghr = acc[0] + bh_r;
            const float ghz = acc[1] + bh_z;
            const float ghn = acc[2] + bh_n;
            const float rg = 1.f / (1.f + __expf(-(xr + ghr)));
            const float zg = 1.f / (1.f + __expf(-(xz + ghz)));
            float a = xn + rg * ghn;
            a = fminf(fmaxf(a, -15.f), 15.f);
            const float e2 = __expf(-2.f * a);
            const float ng = (1.f - e2) / (1.f + e2);   // tanh(a)
            const float hnew = (1.f - zg) * ng + zg * h_own;
            h_own = hnew;
            const unsigned pr = ((unsigned)(t + 1) << 16) |
                (unsigned)__half_as_ushort(__float2half(hnew));
            __hip_atomic_store(pairs + (size_t)((t + 1) & 1) * H_DIM + my_i, pr,
                               __ATOMIC_RELAXED, __HIP_MEMORY_SCOPE_AGENT);
            hsX[(size_t)t * XROW_F32 + my_i] = hnew;   // read after kernel end
        }
    }
}

// ---------------------------------------------------------------------------
extern "C" void kernel_launch(void* const* d_in, const int* in_sizes, int n_in,
                              void* d_out, int out_size, void* d_ws, size_t ws_size,
                              hipStream_t stream) {
    const float* obs  = (const float*)d_in[0];
    const float* W_ih = (const float*)d_in[1];
    const float* W_hh = (const float*)d_in[2];
    const float* b_ih = (const float*)d_in[3];
    const float* b_hh = (const float*)d_in[4];
    const float* W_o  = (const float*)d_in[5];
    const float* b_o  = (const float*)d_in[6];
    const float* W_d  = (const float*)d_in[7];
    const float* b_d  = (const float*)d_in[8];
    float* out = (float*)d_out;

    // Workspace layout (~100.8 MiB total):
    //   [4096, 20480)   h packets (2 x 2048 x 4 B), pre-zeroed
    //   [20480, 24576)  epoch flags: 64 replicated 64B lines, pre-zeroed
    //   [65536, ...)    X buffer: (T+1) rows x 12288 B
    char*     ws    = (char*)d_ws;
    unsigned* pairs = (unsigned*)(ws + 4096);
    unsigned* flags = (unsigned*)(ws + 20480);
    char*     X     = ws + 65536;
    __half*   xiX   = (__half*)X;   // fp16 rows, stride 6144
    float*    hsX   = (float*)X;    // fp32 rows, stride 3072

    hipMemsetAsync(d_ws, 0, 65536, stream);

    // Phase 1: xi[t] = obs @ W_ih.T + b_ih  -> fp16 into X row t+1
    gemm_bt_bias<1><<<dim3(G3 / 128, T_STEPS / 128), 256, 0, stream>>>(
        obs, O_DIM, W_ih, b_ih, (void*)(xiX + G3), G3, T_STEPS, G3, O_DIM);

    // Phase 2: sequential GRU scan (cooperative, 256 WGs x 512 threads)
    {
        void* args[] = { (void*)&xiX, (void*)&hsX, (void*)&W_hh, (void*)&b_hh,
                         (void*)&pairs, (void*)&flags };
        hipLaunchCooperativeKernel((const void*)gru_scan,
                                   dim3(NWG), dim3(512), args, 0, stream);
    }

    // Phase 3: output projections (A = hs rows inside X, lda = 3072)
    gemm_bt_bias<0><<<dim3(A_DIM / 128, T_STEPS / 128), 256, 0, stream>>>(
        (const float*)hsX, XROW_F32, W_o, b_o, (void*)out, A_DIM,
        T_STEPS, A_DIM, H_DIM);
    gemm_bt_bias<0><<<dim3(A_DIM / 128, T_STEPS / 128), 256, 0, stream>>>(
        (const float*)hsX, XROW_F32, W_d, b_d,
        (void*)(out + (size_t)T_STEPS * A_DIM), A_DIM,
        T_STEPS, A_DIM, H_DIM);
}

// Round 6
// 21266.548 us; speedup vs baseline: 1.1929x; 1.1929x over previous
//
#include <hip/hip_runtime.h>
#include <hip/hip_bf16.h>
#include <hip/hip_fp16.h>

// Problem constants
#define T_STEPS 8192
#define O_DIM   1024
#define H_DIM   2048
#define G3      6144      // 3*H
#define A_DIM   512
#define NWG     256       // workgroups in scan (1 per CU)
#define SLICE   8         // hidden indices per WG (= waves per WG)
#define NROWS   24        // 3 * SLICE rows of W_hh per WG
#define RPW     3         // rows per wave (r, z, n gate rows of own idx)

// X buffer rows: row t+1 holds xi[t] as fp16[6144]; hs[t] (fp32[2048]) is
// written into row t after its xi was consumed.
#define XROW_F32   3072

typedef _Float16 v2h __attribute__((ext_vector_type(2)));

__device__ __forceinline__ float dot8(uint4 w, uint4 h, float acc) {
#if defined(__has_builtin) && __has_builtin(__builtin_amdgcn_fdot2)
    acc = __builtin_amdgcn_fdot2(__builtin_bit_cast(v2h, w.x),
                                 __builtin_bit_cast(v2h, h.x), acc, false);
    acc = __builtin_amdgcn_fdot2(__builtin_bit_cast(v2h, w.y),
                                 __builtin_bit_cast(v2h, h.y), acc, false);
    acc = __builtin_amdgcn_fdot2(__builtin_bit_cast(v2h, w.z),
                                 __builtin_bit_cast(v2h, h.z), acc, false);
    acc = __builtin_amdgcn_fdot2(__builtin_bit_cast(v2h, w.w),
                                 __builtin_bit_cast(v2h, h.w), acc, false);
#else
    const __half2* wh = (const __half2*)&w;
    const __half2* hh = (const __half2*)&h;
    #pragma unroll
    for (int q = 0; q < 4; ++q) {
        float2 wf = __half22float2(wh[q]);
        float2 hf = __half22float2(hh[q]);
        acc = fmaf(wf.x, hf.x, acc);
        acc = fmaf(wf.y, hf.y, acc);
    }
#endif
    return acc;
}

// 64-lane sum, VALU-only (DPP). Validated numerically (v8/v9 passed).
__device__ __forceinline__ float dpp_sum64(float v) {
    float s = v;
    int x;
    x = __builtin_amdgcn_update_dpp(0, __builtin_bit_cast(int, s), 0x111, 0xF, 0xF, true);
    s += __builtin_bit_cast(float, x);
    x = __builtin_amdgcn_update_dpp(0, __builtin_bit_cast(int, s), 0x112, 0xF, 0xF, true);
    s += __builtin_bit_cast(float, x);
    x = __builtin_amdgcn_update_dpp(0, __builtin_bit_cast(int, s), 0x114, 0xF, 0xF, true);
    s += __builtin_bit_cast(float, x);
    x = __builtin_amdgcn_update_dpp(0, __builtin_bit_cast(int, s), 0x118, 0xF, 0xF, true);
    s += __builtin_bit_cast(float, x);
    x = __builtin_amdgcn_update_dpp(0, __builtin_bit_cast(int, s), 0x142, 0xF, 0xF, true); // row_bcast15
    s += __builtin_bit_cast(float, x);
    x = __builtin_amdgcn_update_dpp(0, __builtin_bit_cast(int, s), 0x143, 0xF, 0xF, true); // row_bcast31
    s += __builtin_bit_cast(float, x);
    return __builtin_bit_cast(float,
        __builtin_amdgcn_readlane(__builtin_bit_cast(int, s), 63));
}

// ---------------------------------------------------------------------------
// fp32 GEMM:  C[M,N] = A[M,K] @ B[N,K]^T + bias[N]
// 128x128 tile, BK=16, 256 threads, 8x8 per thread.
// OUT_HALF=1 stores C as fp16, else fp32. A row stride lda, C row stride ldc.
// ---------------------------------------------------------------------------
template <int OUT_HALF>
__global__ __launch_bounds__(256) void gemm_bt_bias(
    const float* __restrict__ A, int lda,
    const float* __restrict__ B,
    const float* __restrict__ bias,
    void* __restrict__ Cv, int ldc,
    int M, int N, int K)
{
    __shared__ float As[16][128];
    __shared__ float Bs[16][128];

    const int bm = blockIdx.y * 128;
    const int bn = blockIdx.x * 128;
    const int tid = threadIdx.x;
    const int tm = (tid >> 4) * 8;
    const int tn = (tid & 15) * 8;

    float acc[8][8] = {};

    for (int k0 = 0; k0 < K; k0 += 16) {
        #pragma unroll
        for (int u = 0; u < 2; ++u) {
            const int id = u * 256 + tid;
            const int r = id >> 2;
            const int c = (id & 3) << 2;
            float4 v = *(const float4*)(A + (size_t)(bm + r) * lda + k0 + c);
            As[c + 0][r] = v.x; As[c + 1][r] = v.y;
            As[c + 2][r] = v.z; As[c + 3][r] = v.w;
        }
        #pragma unroll
        for (int u = 0; u < 2; ++u) {
            const int id = u * 256 + tid;
            const int r = id >> 2;
            const int c = (id & 3) << 2;
            float4 v = *(const float4*)(B + (size_t)(bn + r) * K + k0 + c);
            Bs[c + 0][r] = v.x; Bs[c + 1][r] = v.y;
            Bs[c + 2][r] = v.z; Bs[c + 3][r] = v.w;
        }
        __syncthreads();

        #pragma unroll
        for (int kk = 0; kk < 16; ++kk) {
            float a[8], b[8];
            #pragma unroll
            for (int i = 0; i < 8; ++i) a[i] = As[kk][tm + i];
            #pragma unroll
            for (int j = 0; j < 8; ++j) b[j] = Bs[kk][tn + j];
            #pragma unroll
            for (int i = 0; i < 8; ++i)
                #pragma unroll
                for (int j = 0; j < 8; ++j)
                    acc[i][j] = fmaf(a[i], b[j], acc[i][j]);
        }
        __syncthreads();
    }

    if (OUT_HALF) {
        __half* C = (__half*)Cv;
        #pragma unroll
        for (int i = 0; i < 8; ++i) {
            const size_t row = (size_t)(bm + tm + i) * ldc;
            __half tmp[8];
            #pragma unroll
            for (int j = 0; j < 8; ++j)
                tmp[j] = __float2half(acc[i][j] + bias[bn + tn + j]);
            *(uint4*)(C + row + bn + tn) = *(const uint4*)tmp;
        }
    } else {
        float* C = (float*)Cv;
        #pragma unroll
        for (int i = 0; i < 8; ++i) {
            const size_t row = (size_t)(bm + tm + i) * ldc;
            #pragma unroll
            for (int j0 = 0; j0 < 8; j0 += 4) {
                const int n = bn + tn + j0;
                float4 v;
                v.x = acc[i][j0 + 0] + bias[n + 0];
                v.y = acc[i][j0 + 1] + bias[n + 1];
                v.z = acc[i][j0 + 2] + bias[n + 2];
                v.w = acc[i][j0 + 3] + bias[n + 3];
                *(float4*)(C + row + n) = v;
            }
        }
    }
}

// ---------------------------------------------------------------------------
// Persistent cooperative GRU scan, v11 = v9 + 2-byte parity-tagged packets.
// 256 WGs x 512 threads (8 waves). Wave w of WG g owns hidden idx i=8g+w,
// i.e. W_hh rows {w, 8+w, 16+w} (fp16, LDS-resident, 96 KiB).
//
// v10 lesson: the direct packet poll is hop-optimal (discovery == data
// fetch); any flag/summary scheme adds a full visibility round trip
// (+7.5ms). So v11 keeps the direct poll and halves its traffic+requests
// instead: |h| <= 1 always (convex combo of tanh outputs, h0=0), so
// fp16(h) NEVER sets bit14 (values >= 2.0 do). Bit14 = free 1-bit step
// parity tag inside a 2B packet:
//   packet(s) = fp16bits(h[s-1]) | (((s>>1)&1) << 14), row = s&1.
// Adjacent occupants of a row (steps s, s+2) differ in parity; ambiguity
// needs skew >= 4 steps, impossible (a WG at step t certified all stores
// of t-1, so every WG passed poll t-2 — max skew ~1). Pre-init: row0 = 0x00
// (parity 0, value 0.0 = h0, ready for s=0), row1 = 0x40 bytes (bit14=1,
// not-ready for s=1). Same-address store ordering per producer lane gives
// coherence order ✓. Poll: ONE 8B load/lane/iter (was two) — 2x fewer
// requests and bytes at the L3 coherence point. Stage: v & 0xBFFF mask
// yields clean fp16 directly.
// ---------------------------------------------------------------------------
__global__ __launch_bounds__(512) void gru_scan(
    const __half*    __restrict__ xiX,     // X as fp16 rows (stride 6144)
    float*           __restrict__ hsX,     // X as fp32 rows (stride 3072)
    const float*     __restrict__ W_hh,    // [6144, 2048]
    const float*     __restrict__ b_hh,    // [6144]
    unsigned short*  __restrict__ pairs)   // [2][2048] u16 packets, pre-init
{
    const int g    = blockIdx.x;
    const int tid  = threadIdx.x;
    const int wave = tid >> 6;
    const int lane = tid & 63;
    const int my_i = g * SLICE + wave;   // hidden index owned by this wave

    __shared__ __align__(16) __half w_lds[NROWS][H_DIM];   // 96 KiB
    __shared__ __align__(16) __half h_lds[2][H_DIM];       // 8 KiB

    // ---- preload W_hh slice -> fp16 LDS (coalesced float4 loads) ----------
    for (int l = 0; l < NROWS; ++l) {
        const int grow = (l >> 3) * H_DIM + g * SLICE + (l & 7);
        float4 v = *(const float4*)(W_hh + (size_t)grow * H_DIM + tid * 4);
        __half tmp[4] = { __float2half(v.x), __float2half(v.y),
                          __float2half(v.z), __float2half(v.w) };
        *(uint2*)(&w_lds[l][tid * 4]) = *(const uint2*)tmp;
    }
    float bh_r = 0.f, bh_z = 0.f, bh_n = 0.f;
    if (lane == 0) {
        bh_r = b_hh[my_i];
        bh_z = b_hh[H_DIM + my_i];
        bh_n = b_hh[2 * H_DIM + my_i];
    }
    __syncthreads();

    float h_own = 0.f;   // lane0: fp32 hidden value of own index
    const unsigned long long M14 = 0x0001000100010001ull;  // bit14->bit0 mask

    for (int t = 0; t < T_STEPS; ++t) {
        // lane0: prefetch xi for this step (row t+1 of X), plain cached loads
        float xr = 0.f, xz = 0.f, xn = 0.f;
        if (lane == 0) {
            const __half* xp = xiX + (size_t)(t + 1) * G3 + my_i;
            xr = __half2float(xp[0]);
            xz = __half2float(xp[H_DIM]);
            xn = __half2float(xp[2 * H_DIM]);
        }

        // issue weight ds_reads now: LDS port works during the poll wait
        uint4 wv[RPW][4];
        #pragma unroll
        for (int r = 0; r < RPW; ++r)
            #pragma unroll
            for (int j = 0; j < 4; ++j)
                wv[r][j] = *(const uint4*)(&w_lds[r * 8 + wave][j * 512 + lane * 8]);

        // poll own chunk of 256 packets (4/lane, ONE 8B load), stage into
        // h_lds[t&1]. Ready iff every u16's bit14 == parity(t).
        {
            const unsigned long long* pp = (const unsigned long long*)
                (pairs + (size_t)(t & 1) * H_DIM + wave * 256 + lane * 4);
            const unsigned long long want = ((t >> 1) & 1) ? M14 : 0ull;
            unsigned long long v;
            for (;;) {
                v = __hip_atomic_load(pp, __ATOMIC_RELAXED,
                                      __HIP_MEMORY_SCOPE_AGENT);
                bool ok = (((v >> 14) & M14) == want);
                if (__all(ok)) break;
                __builtin_amdgcn_s_sleep(1);
            }
            const unsigned long long hbits = v & 0xBFFFBFFFBFFFBFFFull;
            *(unsigned long long*)(&h_lds[t & 1][wave * 256 + lane * 4]) = hbits;
        }
        __syncthreads();   // h_lds[t&1] ready

        // matvec: 3 rows x 2048 via fp16 dot2, fp32 accumulate
        uint4 hv[4];
        #pragma unroll
        for (int j = 0; j < 4; ++j)
            hv[j] = *(const uint4*)(&h_lds[t & 1][j * 512 + lane * 8]);

        float acc[RPW] = {0.f, 0.f, 0.f};
        #pragma unroll
        for (int r = 0; r < RPW; ++r)
            #pragma unroll
            for (int j = 0; j < 4; ++j)
                acc[r] = dot8(wv[r][j], hv[j], acc[r]);

        // 64-lane sum per row, DPP-only (no LDS port on the critical path)
        #pragma unroll
        for (int r = 0; r < RPW; ++r)
            acc[r] = dpp_sum64(acc[r]);

        // lane0: gates + publish
        if (lane == 0) {
            const float ghr = acc[0] + bh_r;
            const float ghz = acc[1] + bh_z;
            const float ghn = acc[2] + bh_n;
            const float rg = 1.f / (1.f + __expf(-(xr + ghr)));
            const float zg = 1.f / (1.f + __expf(-(xz + ghz)));
            float a = xn + rg * ghn;
            a = fminf(fmaxf(a, -15.f), 15.f);
            const float e2 = __expf(-2.f * a);
            const float ng = (1.f - e2) / (1.f + e2);   // tanh(a)
            const float hnew = (1.f - zg) * ng + zg * h_own;
            h_own = hnew;
            // packet for consumption step s = t+1: row s&1, parity (s>>1)&1
            const unsigned short pr = (unsigned short)
                (__half_as_ushort(__float2half(hnew)) |
                 ((((unsigned)(t + 1) >> 1) & 1u) << 14));
            __hip_atomic_store(pairs + (size_t)((t + 1) & 1) * H_DIM + my_i, pr,
                               __ATOMIC_RELAXED, __HIP_MEMORY_SCOPE_AGENT);
            hsX[(size_t)t * XROW_F32 + my_i] = hnew;   // read after kernel end
        }
    }
}

// ---------------------------------------------------------------------------
extern "C" void kernel_launch(void* const* d_in, const int* in_sizes, int n_in,
                              void* d_out, int out_size, void* d_ws, size_t ws_size,
                              hipStream_t stream) {
    const float* obs  = (const float*)d_in[0];
    const float* W_ih = (const float*)d_in[1];
    const float* W_hh = (const float*)d_in[2];
    const float* b_ih = (const float*)d_in[3];
    const float* b_hh = (const float*)d_in[4];
    const float* W_o  = (const float*)d_in[5];
    const float* b_o  = (const float*)d_in[6];
    const float* W_d  = (const float*)d_in[7];
    const float* b_d  = (const float*)d_in[8];
    float* out = (float*)d_out;

    // Workspace layout (~100.8 MiB total):
    //   [4096, 8192)    h packets row 0 (2048 x u16), init 0x00 (ready s=0)
    //   [8192, 12288)   h packets row 1 (2048 x u16), init 0x40 (not ready)
    //   [65536, ...)    X buffer: (T+1) rows x 12288 B
    char*           ws    = (char*)d_ws;
    unsigned short* pairs = (unsigned short*)(ws + 4096);
    char*           X     = ws + 65536;
    __half*         xiX   = (__half*)X;   // fp16 rows, stride 6144
    float*          hsX   = (float*)X;    // fp32 rows, stride 3072

    hipMemsetAsync(d_ws, 0, 65536, stream);
    // row1: every u16 = 0x4040 -> bit14 = 1 -> parity 1 != parity(s=1)=0
    hipMemsetAsync(ws + 8192, 0x40, 4096, stream);

    // Phase 1: xi[t] = obs @ W_ih.T + b_ih  -> fp16 into X row t+1
    gemm_bt_bias<1><<<dim3(G3 / 128, T_STEPS / 128), 256, 0, stream>>>(
        obs, O_DIM, W_ih, b_ih, (void*)(xiX + G3), G3, T_STEPS, G3, O_DIM);

    // Phase 2: sequential GRU scan (cooperative, 256 WGs x 512 threads)
    {
        void* args[] = { (void*)&xiX, (void*)&hsX, (void*)&W_hh, (void*)&b_hh,
                         (void*)&pairs };
        hipLaunchCooperativeKernel((const void*)gru_scan,
                                   dim3(NWG), dim3(512), args, 0, stream);
    }

    // Phase 3: output projections (A = hs rows inside X, lda = 3072)
    gemm_bt_bias<0><<<dim3(A_DIM / 128, T_STEPS / 128), 256, 0, stream>>>(
        (const float*)hsX, XROW_F32, W_o, b_o, (void*)out, A_DIM,
        T_STEPS, A_DIM, H_DIM);
    gemm_bt_bias<0><<<dim3(A_DIM / 128, T_STEPS / 128), 256, 0, stream>>>(
        (const float*)hsX, XROW_F32, W_d, b_d,
        (void*)(out + (size_t)T_STEPS * A_DIM), A_DIM,
        T_STEPS, A_DIM, H_DIM);
}